// Round 1
// baseline (2329.292 us; speedup 1.0000x reference)
//
#include <hip/hip_runtime.h>
#include <stdint.h>

typedef unsigned short u16;
typedef unsigned int u32;

#define BB 16
#define CC 32
#define NN 512
#define TT 256
#define NT (NN*TT)            // 131072
#define BCNT (BB*CC*NT)       // 67108864
#define ALPHA 0.05f
#define BETAC 0.95f

__device__ __forceinline__ float bf2f(u16 u){ return __uint_as_float(((u32)u) << 16); }
__device__ __forceinline__ u16 f2bf(float f){
    u32 b = __float_as_uint(f);
    u32 r = (b + 0x7FFFu + ((b >> 16) & 1u)) >> 16;
    return (u16)r;
}

// ---------------------------------------------------------------------------
// K0: adj row-normalize + combined MLP weights
// grid: 512 blocks (one per adj row), 256 threads
__global__ void k0_prep(const float* __restrict__ adj, const float* __restrict__ mlpw,
                        float* __restrict__ adjn, float* __restrict__ wc){
    int i = blockIdx.x;
    int tid = threadIdx.x;
    float a0 = adj[i*NN + tid];
    float a1 = adj[i*NN + tid + 256];
    float s = a0 + a1;
    for (int off = 32; off; off >>= 1) s += __shfl_down(s, off);
    __shared__ float wsum[4];
    if ((tid & 63) == 0) wsum[tid >> 6] = s;
    __syncthreads();
    float inv = 1.0f / (wsum[0] + wsum[1] + wsum[2] + wsum[3] + 1e-8f);
    adjn[i*NN + tid]       = a0 * inv;
    adjn[i*NN + tid + 256] = a1 * inv;
    if (blockIdx.x == 0){
        for (int idx = tid; idx < 1024; idx += 256){
            int o = idx >> 5, c = idx & 31;
            float m0 = mlpw[o*96 + c];
            float m1 = mlpw[o*96 + 32 + c];
            float m2 = mlpw[o*96 + 64 + c];
            wc[idx]        = m0 + ALPHA*(m1 + m2);          // Wh
            wc[1024 + idx] = BETAC*(m1 + ALPHA*m2);         // W1
            wc[2048 + idx] = BETAC*BETAC*m2;                // W2
        }
    }
}

// ---------------------------------------------------------------------------
// K1: gated temporal conv: h = tanh(filt)*sigmoid(gate), h -> bf16 ws
// grid: B*N blocks, 256 threads (thread = t)
__global__ __launch_bounds__(256) void k1_gate(
    const float* __restrict__ x,
    const float* __restrict__ fw, const float* __restrict__ fb,
    const float* __restrict__ gw, const float* __restrict__ gb,
    u16* __restrict__ hOut){
    __shared__ float xs[CC][TT + 4];
    __shared__ float fwl[CC*CC*2];
    __shared__ float gwl[CC*CC*2];
    int tid = threadIdx.x;
    int blk = blockIdx.x;
    int b = blk >> 9, n = blk & 511;
    for (int idx = tid; idx < CC*CC*2; idx += 256){ fwl[idx] = fw[idx]; gwl[idx] = gw[idx]; }
    const float* xb = x + (size_t)(b*CC)*NT + (size_t)n*TT;
    #pragma unroll
    for (int c = 0; c < CC; ++c) xs[c][tid] = xb[(size_t)c*NT + tid];
    if (tid < CC) xs[tid][TT] = 0.0f;   // right zero-pad (x[T] = 0)
    __syncthreads();
    float x0[CC], x1[CC];
    #pragma unroll
    for (int c = 0; c < CC; ++c){ x0[c] = xs[c][tid]; x1[c] = xs[c][tid + 1]; }
    u16* hb = hOut + (size_t)(b*CC)*NT + (size_t)n*TT + tid;
    for (int o = 0; o < CC; ++o){
        float fa = fb[o], ga = gb[o];
        #pragma unroll
        for (int c = 0; c < CC; ++c){
            fa = fmaf(x0[c], fwl[(o*CC + c)*2 + 0], fa);
            fa = fmaf(x1[c], fwl[(o*CC + c)*2 + 1], fa);
            ga = fmaf(x0[c], gwl[(o*CC + c)*2 + 0], ga);
            ga = fmaf(x1[c], gwl[(o*CC + c)*2 + 1], ga);
        }
        float th = 1.0f - 2.0f / (__expf(2.0f*fa) + 1.0f);   // tanh
        float sg = 1.0f / (1.0f + __expf(-ga));              // sigmoid
        hb[(size_t)o*NT] = f2bf(th * sg);
    }
}

// ---------------------------------------------------------------------------
// K2: batched GEMM  dst[bc][i][t] = sum_j adjn[i][j] * src[bc][j][t]
// tile 128x128, BK=16, 256 threads, 8x8 micro-tile (split 4+4 across halves)
// grid: (4 i-tiles, 2 t-tiles, 512 bc)
__global__ __launch_bounds__(256) void k2_gemm(
    const float* __restrict__ adjn, const u16* __restrict__ src,
    void* __restrict__ dst, int dstF32){
    __shared__ float As[16][132];   // [k][i], padded
    __shared__ float Bs[16][128];   // [k][t]
    int tid = threadIdx.x;
    int tx = tid & 15, ty = tid >> 4;
    int i0 = blockIdx.x * 128;
    int t0 = blockIdx.y * 128;
    int bc = blockIdx.z;
    const u16* srcb = src + (size_t)bc * NT;
    float acc[8][8];
    #pragma unroll
    for (int r = 0; r < 8; ++r)
        #pragma unroll
        for (int c = 0; c < 8; ++c) acc[r][c] = 0.0f;

    int sa_i = tid >> 1, sa_kh = (tid & 1) * 8;
    int sb_k = tid >> 4, sb_t = (tid & 15) * 8;

    for (int kb = 0; kb < 32; ++kb){
        int k0 = kb * 16;
        __syncthreads();
        {   // stage A (f32, transposed into [k][i])
            const float* ap = adjn + (size_t)(i0 + sa_i)*NN + k0 + sa_kh;
            float4 v0 = *(const float4*)ap;
            float4 v1 = *(const float4*)(ap + 4);
            As[sa_kh+0][sa_i] = v0.x; As[sa_kh+1][sa_i] = v0.y;
            As[sa_kh+2][sa_i] = v0.z; As[sa_kh+3][sa_i] = v0.w;
            As[sa_kh+4][sa_i] = v1.x; As[sa_kh+5][sa_i] = v1.y;
            As[sa_kh+6][sa_i] = v1.z; As[sa_kh+7][sa_i] = v1.w;
        }
        {   // stage B (bf16 -> f32)
            const u16* hp = srcb + (size_t)(k0 + sb_k)*TT + t0 + sb_t;
            u32 const* hp32 = (u32 const*)hp;
            uint4 u = *(const uint4*)hp32;
            Bs[sb_k][sb_t+0] = __uint_as_float(u.x << 16);
            Bs[sb_k][sb_t+1] = __uint_as_float(u.x & 0xFFFF0000u);
            Bs[sb_k][sb_t+2] = __uint_as_float(u.y << 16);
            Bs[sb_k][sb_t+3] = __uint_as_float(u.y & 0xFFFF0000u);
            Bs[sb_k][sb_t+4] = __uint_as_float(u.z << 16);
            Bs[sb_k][sb_t+5] = __uint_as_float(u.z & 0xFFFF0000u);
            Bs[sb_k][sb_t+6] = __uint_as_float(u.w << 16);
            Bs[sb_k][sb_t+7] = __uint_as_float(u.w & 0xFFFF0000u);
        }
        __syncthreads();
        #pragma unroll
        for (int kk = 0; kk < 16; ++kk){
            float4 alo = *(const float4*)&As[kk][ty*4];
            float4 ahi = *(const float4*)&As[kk][64 + ty*4];
            float4 blo = *(const float4*)&Bs[kk][tx*4];
            float4 bhi = *(const float4*)&Bs[kk][64 + tx*4];
            float av[8] = {alo.x, alo.y, alo.z, alo.w, ahi.x, ahi.y, ahi.z, ahi.w};
            float bv[8] = {blo.x, blo.y, blo.z, blo.w, bhi.x, bhi.y, bhi.z, bhi.w};
            #pragma unroll
            for (int r = 0; r < 8; ++r)
                #pragma unroll
                for (int c = 0; c < 8; ++c)
                    acc[r][c] = fmaf(av[r], bv[c], acc[r][c]);
        }
    }
    float* dF = (float*)dst;
    u16*   dH = (u16*)dst;
    #pragma unroll
    for (int r = 0; r < 8; ++r){
        int i = i0 + ((r < 4) ? (ty*4 + r) : (64 + ty*4 + r - 4));
        size_t ro = (size_t)bc*NT + (size_t)i*TT + t0;
        if (dstF32){
            float4 v0 = {acc[r][0], acc[r][1], acc[r][2], acc[r][3]};
            float4 v1 = {acc[r][4], acc[r][5], acc[r][6], acc[r][7]};
            *(float4*)(dF + ro + tx*4)      = v0;
            *(float4*)(dF + ro + 64 + tx*4) = v1;
        } else {
            ushort4 v0, v1;
            v0.x = f2bf(acc[r][0]); v0.y = f2bf(acc[r][1]);
            v0.z = f2bf(acc[r][2]); v0.w = f2bf(acc[r][3]);
            v1.x = f2bf(acc[r][4]); v1.y = f2bf(acc[r][5]);
            v1.z = f2bf(acc[r][6]); v1.w = f2bf(acc[r][7]);
            *(ushort4*)(dH + ro + tx*4)      = v0;
            *(ushort4*)(dH + ro + 64 + tx*4) = v1;
        }
    }
}

// ---------------------------------------------------------------------------
// K4: y = Wh*h + W1*g1 + W2*g2 + mlp_b (g2 read from d_out, y written in place)
//     + deterministic per-block channel sums for BN
// grid: B*N blocks, 256 threads (thread = t)
__global__ __launch_bounds__(256) void k4_mix(
    const u16* __restrict__ h, const u16* __restrict__ g1,
    float* __restrict__ y, const float* __restrict__ wc,
    const float* __restrict__ mlpb,
    float* __restrict__ psum, float* __restrict__ psq){
    __shared__ float wl[3*1024];
    __shared__ float wsum[4][CC], wsq[4][CC];
    int tid = threadIdx.x;
    int blk = blockIdx.x;
    int b = blk >> 9, n = blk & 511;
    for (int idx = tid; idx < 3072; idx += 256) wl[idx] = wc[idx];
    size_t base = (size_t)(b*CC)*NT + (size_t)n*TT + tid;
    float hv[CC], g1v[CC], g2v[CC];
    #pragma unroll
    for (int c = 0; c < CC; ++c){
        hv[c]  = bf2f(h [base + (size_t)c*NT]);
        g1v[c] = bf2f(g1[base + (size_t)c*NT]);
        g2v[c] = y[base + (size_t)c*NT];
    }
    __syncthreads();
    int lane = tid & 63, wv = tid >> 6;
    for (int o = 0; o < CC; ++o){
        float acc = mlpb[o];
        #pragma unroll
        for (int c = 0; c < CC; ++c){
            acc = fmaf(hv[c],  wl[o*CC + c],        acc);
            acc = fmaf(g1v[c], wl[1024 + o*CC + c], acc);
            acc = fmaf(g2v[c], wl[2048 + o*CC + c], acc);
        }
        y[base + (size_t)o*NT] = acc;
        float s = acc, q = acc*acc;
        for (int off = 32; off; off >>= 1){
            s += __shfl_down(s, off);
            q += __shfl_down(q, off);
        }
        if (lane == 0){ wsum[wv][o] = s; wsq[wv][o] = q; }
    }
    __syncthreads();
    if (tid < CC){
        psum[(size_t)tid*8192 + blk] = wsum[0][tid] + wsum[1][tid] + wsum[2][tid] + wsum[3][tid];
    } else if (tid < 2*CC){
        int o = tid - CC;
        psq[(size_t)o*8192 + blk] = wsq[0][o] + wsq[1][o] + wsq[2][o] + wsq[3][o];
    }
}

// ---------------------------------------------------------------------------
// K5: finalize BN stats -> scale/shift per channel (deterministic tree)
// grid: 32 blocks (one per channel), 256 threads
__global__ void k5_stats(const float* __restrict__ psum, const float* __restrict__ psq,
                         const float* __restrict__ gamma, const float* __restrict__ beta,
                         float* __restrict__ ss){
    int o = blockIdx.x, tid = threadIdx.x;
    double s = 0.0, q = 0.0;
    for (int k = 0; k < 32; ++k){
        s += (double)psum[(size_t)o*8192 + tid + k*256];
        q += (double)psq [(size_t)o*8192 + tid + k*256];
    }
    __shared__ double sd[256], qd[256];
    sd[tid] = s; qd[tid] = q;
    __syncthreads();
    for (int off = 128; off; off >>= 1){
        if (tid < off){ sd[tid] += sd[tid + off]; qd[tid] += qd[tid + off]; }
        __syncthreads();
    }
    if (tid == 0){
        double cnt = (double)BB * NN * TT;
        double mean = sd[0] / cnt;
        double var  = qd[0] / cnt - mean*mean;
        float scale = gamma[o] * (float)(1.0 / sqrt(var + 1e-5));
        float shift = beta[o] - (float)mean * scale;
        ss[o]      = scale;
        ss[CC + o] = shift;
    }
}

// ---------------------------------------------------------------------------
// K6: out = relu(y*scale + shift + res_w@x + res_b), in place on d_out
// grid: B*N blocks, 256 threads (thread = t)
__global__ __launch_bounds__(256) void k6_final(
    const float* __restrict__ x, const float* __restrict__ rw,
    const float* __restrict__ rb, const float* __restrict__ ss,
    float* __restrict__ y){
    __shared__ float rwl[CC*CC];
    __shared__ float ssl[2*CC];
    int tid = threadIdx.x;
    int blk = blockIdx.x;
    int b = blk >> 9, n = blk & 511;
    for (int idx = tid; idx < CC*CC; idx += 256) rwl[idx] = rw[idx];
    if (tid < 2*CC) ssl[tid] = ss[tid];
    size_t base = (size_t)(b*CC)*NT + (size_t)n*TT + tid;
    float xv[CC];
    #pragma unroll
    for (int c = 0; c < CC; ++c) xv[c] = x[base + (size_t)c*NT];
    __syncthreads();
    for (int o = 0; o < CC; ++o){
        float res = rb[o];
        #pragma unroll
        for (int c = 0; c < CC; ++c) res = fmaf(xv[c], rwl[o*CC + c], res);
        float v = y[base + (size_t)o*NT] * ssl[o] + ssl[CC + o] + res;
        y[base + (size_t)o*NT] = v > 0.0f ? v : 0.0f;
    }
}

// ---------------------------------------------------------------------------
extern "C" void kernel_launch(void* const* d_in, const int* in_sizes, int n_in,
                              void* d_out, int out_size, void* d_ws, size_t ws_size,
                              hipStream_t stream){
    const float* x     = (const float*)d_in[0];
    const float* adj   = (const float*)d_in[1];
    const float* fw    = (const float*)d_in[2];
    const float* fb    = (const float*)d_in[3];
    const float* gw    = (const float*)d_in[4];
    const float* gb    = (const float*)d_in[5];
    const float* mlpw  = (const float*)d_in[6];
    const float* mlpb  = (const float*)d_in[7];
    const float* rw    = (const float*)d_in[8];
    const float* rb    = (const float*)d_in[9];
    const float* gamma = (const float*)d_in[10];
    const float* beta  = (const float*)d_in[11];
    float* out = (float*)d_out;

    char* ws = (char*)d_ws;
    u16*   h_ws  = (u16*)(ws);                                   // 134,217,728 B
    u16*   g1_ws = (u16*)(ws + (size_t)BCNT*2);                  // 134,217,728 B
    float* adjn  = (float*)(ws + (size_t)BCNT*4);                // 1,048,576 B
    float* wc    = (float*)(ws + (size_t)BCNT*4 + (size_t)NN*NN*4);          // 12,288 B
    float* ss    = (float*)(ws + (size_t)BCNT*4 + (size_t)NN*NN*4 + 12288);  // 256 B
    float* psum  = (float*)(ws + (size_t)BCNT*4 + (size_t)NN*NN*4 + 12288 + 256); // 1 MB
    float* psq   = psum + (size_t)CC*8192;                       // 1 MB

    k0_prep <<<NN, 256, 0, stream>>>(adj, mlpw, adjn, wc);
    k1_gate <<<BB*NN, 256, 0, stream>>>(x, fw, fb, gw, gb, h_ws);
    k2_gemm <<<dim3(4, 2, 512), 256, 0, stream>>>(adjn, h_ws, (void*)g1_ws, 0);
    k2_gemm <<<dim3(4, 2, 512), 256, 0, stream>>>(adjn, g1_ws, (void*)out, 1);
    k4_mix  <<<BB*NN, 256, 0, stream>>>(h_ws, g1_ws, out, wc, mlpb, psum, psq);
    k5_stats<<<CC, 256, 0, stream>>>(psum, psq, gamma, beta, ss);
    k6_final<<<BB*NN, 256, 0, stream>>>(x, rw, rb, ss, out);
}

// Round 3
// 1271.095 us; speedup vs baseline: 1.8325x; 1.8325x over previous
//
#include <hip/hip_runtime.h>
#include <stdint.h>

typedef unsigned short u16;
typedef unsigned int u32;
typedef unsigned long long u64;

#define BB 16
#define CC 32
#define NN 512
#define TT 256
#define NT (NN*TT)            // 131072
#define BCNT (BB*CC*NT)       // 67108864
#define ALPHA 0.05f
#define BETAC 0.95f

typedef __attribute__((ext_vector_type(8))) short short8v;
typedef __attribute__((ext_vector_type(4))) float f32x4;

__device__ __forceinline__ float bf2f(u16 u){ return __uint_as_float(((u32)u) << 16); }
__device__ __forceinline__ u16 f2bf(float f){
    u32 b = __float_as_uint(f);
    u32 r = (b + 0x7FFFu + ((b >> 16) & 1u)) >> 16;
    return (u16)r;
}

// Shared LDS slot function for the B tile: layout [t(128)][slot(8)] of 16B
// chunks; slot = chunk ^ (t&7) ^ ((t>>2)&7). Pure bijection in chunk for
// fixed t; used identically by writer and reader, so only bank spread (not
// correctness) depends on it.
__device__ __forceinline__ u32 bslot_addr(int chunk, int t){
    int slot = chunk ^ (t & 7) ^ ((t >> 2) & 7);
    return (u32)((t * 8 + slot) * 16);
}

// ---------------------------------------------------------------------------
// K0: adj row-normalize (-> bf16 for MFMA A-operand) + combined MLP weights
__global__ void k0_prep(const float* __restrict__ adj, const float* __restrict__ mlpw,
                        u16* __restrict__ adjb, float* __restrict__ wc){
    int i = blockIdx.x;
    int tid = threadIdx.x;
    float a0 = adj[i*NN + tid];
    float a1 = adj[i*NN + tid + 256];
    float s = a0 + a1;
    for (int off = 32; off; off >>= 1) s += __shfl_down(s, off);
    __shared__ float wsum[4];
    if ((tid & 63) == 0) wsum[tid >> 6] = s;
    __syncthreads();
    float inv = 1.0f / (wsum[0] + wsum[1] + wsum[2] + wsum[3] + 1e-8f);
    adjb[i*NN + tid]       = f2bf(a0 * inv);
    adjb[i*NN + tid + 256] = f2bf(a1 * inv);
    if (blockIdx.x == 0){
        for (int idx = tid; idx < 1024; idx += 256){
            int o = idx >> 5, c = idx & 31;
            float m0 = mlpw[o*96 + c];
            float m1 = mlpw[o*96 + 32 + c];
            float m2 = mlpw[o*96 + 64 + c];
            wc[idx]        = m0 + ALPHA*(m1 + m2);          // Wh
            wc[1024 + idx] = BETAC*(m1 + ALPHA*m2);         // W1
            wc[2048 + idx] = BETAC*BETAC*m2;                // W2
        }
    }
}

// ---------------------------------------------------------------------------
// K1: gated temporal conv: h = tanh(filt)*sigmoid(gate), h -> bf16 ws
__global__ __launch_bounds__(256) void k1_gate(
    const float* __restrict__ x,
    const float* __restrict__ fw, const float* __restrict__ fb,
    const float* __restrict__ gw, const float* __restrict__ gb,
    u16* __restrict__ hOut){
    __shared__ float xs[CC][TT + 4];
    __shared__ float fwl[CC*CC*2];
    __shared__ float gwl[CC*CC*2];
    int tid = threadIdx.x;
    int blk = blockIdx.x;
    int b = blk >> 9, n = blk & 511;
    for (int idx = tid; idx < CC*CC*2; idx += 256){ fwl[idx] = fw[idx]; gwl[idx] = gw[idx]; }
    const float* xb = x + (size_t)(b*CC)*NT + (size_t)n*TT;
    #pragma unroll
    for (int c = 0; c < CC; ++c) xs[c][tid] = xb[(size_t)c*NT + tid];
    if (tid < CC) xs[tid][TT] = 0.0f;   // right zero-pad (x[T] = 0)
    __syncthreads();
    float x0[CC], x1[CC];
    #pragma unroll
    for (int c = 0; c < CC; ++c){ x0[c] = xs[c][tid]; x1[c] = xs[c][tid + 1]; }
    u16* hb = hOut + (size_t)(b*CC)*NT + (size_t)n*TT + tid;
    for (int o = 0; o < CC; ++o){
        float fa = fb[o], ga = gb[o];
        #pragma unroll
        for (int c = 0; c < CC; ++c){
            fa = fmaf(x0[c], fwl[(o*CC + c)*2 + 0], fa);
            fa = fmaf(x1[c], fwl[(o*CC + c)*2 + 1], fa);
            ga = fmaf(x0[c], gwl[(o*CC + c)*2 + 0], ga);
            ga = fmaf(x1[c], gwl[(o*CC + c)*2 + 1], ga);
        }
        float th = 1.0f - 2.0f / (__expf(2.0f*fa) + 1.0f);   // tanh
        float sg = 1.0f / (1.0f + __expf(-ga));              // sigmoid
        hb[(size_t)o*NT] = f2bf(th * sg);
    }
}

// ---------------------------------------------------------------------------
// K2 (MFMA): dst[bc][i][t] = sum_j adjb[i][j] * src[bc][j][t]
// 128x128 tile, BK=64, 4 waves (2x2), 16x16x32 bf16 MFMA.
// A-fragments: direct global 16B loads from adjb (k-contiguous; L2-resident).
// B: reg-staged transpose: each thread loads 8 rows x 4 t (8B each), repacks
//    in-register to 8-k-contiguous 16B chunks, ds_write_b128 to the XOR-slot
//    layout. Fragment reads use the same slot function.
template<int DSTF32>
__global__ __launch_bounds__(256) void k2_mfma(
    const u16* __restrict__ adjb, const u16* __restrict__ src, void* __restrict__ dst){
    __shared__ __align__(16) u16 Bl[128*64];   // 16 KiB: [t][slot] 16B chunks
    const int tid = threadIdx.x;
    const int lane = tid & 63, w = tid >> 6;
    const int wm = w >> 1, wn = w & 1;
    const int g = lane >> 4, c16 = lane & 15;
    const int i0 = blockIdx.x * 128;
    const int t0 = blockIdx.y * 128;
    const int bc = blockIdx.z;
    const u16* srcb = src + (size_t)bc * NT;

    // B staging ownership: thread -> (chunk, 4 consecutive t)
    const int s_chunk = tid >> 5;          // 0..7  (8 k's each)
    const int s_tq    = tid & 31;          // t quad index
    const int s_tb    = s_tq * 4;          // local t base

    f32x4 acc[4][4];
    #pragma unroll
    for (int mi = 0; mi < 4; ++mi)
        #pragma unroll
        for (int ni = 0; ni < 4; ++ni) acc[mi][ni] = (f32x4){0.f,0.f,0.f,0.f};

    // A row base addresses (bf16 elements)
    const u16* arow[4];
    #pragma unroll
    for (int mi = 0; mi < 4; ++mi)
        arow[mi] = adjb + (size_t)(i0 + wm*64 + mi*16 + c16) * NN;

    for (int step = 0; step < 8; ++step){
        const int k0 = step * 64;
        // ---- load B sub-rows to registers (no LDS touched yet) ----
        uint2 v[8];
        #pragma unroll
        for (int r = 0; r < 8; ++r)
            v[r] = *(const uint2*)(srcb + (size_t)(k0 + s_chunk*8 + r)*TT + t0 + s_tb);
        __syncthreads();   // prior step's fragment reads complete
        // ---- repack: for each of 4 t's, 8 k-values -> one 16B chunk ----
        #pragma unroll
        for (int j = 0; j < 4; ++j){
            u32 d[4];
            #pragma unroll
            for (int p = 0; p < 4; ++p){
                u32 lo = (j < 2) ? v[2*p].x   : v[2*p].y;
                u32 hi = (j < 2) ? v[2*p+1].x : v[2*p+1].y;
                u32 sh = (j & 1) * 16;
                u32 e0 = (lo >> sh) & 0xFFFFu;
                u32 e1 = (hi >> sh) & 0xFFFFu;
                d[p] = e0 | (e1 << 16);
            }
            uint4 q = {d[0], d[1], d[2], d[3]};
            *(uint4*)((char*)Bl + bslot_addr(s_chunk, s_tb + j)) = q;
        }
        __syncthreads();   // staging visible
        // ---- compute ----
        #pragma unroll
        for (int kc = 0; kc < 2; ++kc){
            short8v a[4];
            #pragma unroll
            for (int mi = 0; mi < 4; ++mi)
                a[mi] = *(const short8v*)(arow[mi] + k0 + kc*32 + g*8);
            short8v b[4];
            #pragma unroll
            for (int ni = 0; ni < 4; ++ni){
                int t_loc = wn*64 + ni*16 + c16;
                b[ni] = *(const short8v*)((const char*)Bl + bslot_addr(kc*4 + g, t_loc));
            }
            #pragma unroll
            for (int mi = 0; mi < 4; ++mi)
                #pragma unroll
                for (int ni = 0; ni < 4; ++ni)
                    acc[mi][ni] = __builtin_amdgcn_mfma_f32_16x16x32_bf16(
                        a[mi], b[ni], acc[mi][ni], 0, 0, 0);
        }
    }

    // epilogue: D col = lane&15 (t), row = (lane>>4)*4 + r (i)  [m89/m91]
    if (DSTF32){
        float* d = (float*)dst + (size_t)bc * NT;
        #pragma unroll
        for (int mi = 0; mi < 4; ++mi)
            #pragma unroll
            for (int ni = 0; ni < 4; ++ni){
                int tt = t0 + wn*64 + ni*16 + c16;
                int ib = i0 + wm*64 + mi*16 + g*4;
                #pragma unroll
                for (int r = 0; r < 4; ++r)
                    d[(size_t)(ib + r)*TT + tt] = acc[mi][ni][r];
            }
    } else {
        u16* d = (u16*)dst + (size_t)bc * NT;
        #pragma unroll
        for (int mi = 0; mi < 4; ++mi)
            #pragma unroll
            for (int ni = 0; ni < 4; ++ni){
                int tt = t0 + wn*64 + ni*16 + c16;
                int ib = i0 + wm*64 + mi*16 + g*4;
                #pragma unroll
                for (int r = 0; r < 4; ++r)
                    d[(size_t)(ib + r)*TT + tt] = f2bf(acc[mi][ni][r]);
            }
    }
}

// ---------------------------------------------------------------------------
// K4: y = Wh*h + W1*g1 + W2*g2 + mlp_b (g2 in d_out, y in place) + BN partials
__global__ __launch_bounds__(256) void k4_mix(
    const u16* __restrict__ h, const u16* __restrict__ g1,
    float* __restrict__ y, const float* __restrict__ wc,
    const float* __restrict__ mlpb,
    float* __restrict__ psum, float* __restrict__ psq){
    __shared__ float wl[3*1024];
    __shared__ float wsum[4][CC], wsq[4][CC];
    int tid = threadIdx.x;
    int blk = blockIdx.x;
    int b = blk >> 9, n = blk & 511;
    for (int idx = tid; idx < 3072; idx += 256) wl[idx] = wc[idx];
    size_t base = (size_t)(b*CC)*NT + (size_t)n*TT + tid;
    float hv[CC], g1v[CC], g2v[CC];
    #pragma unroll
    for (int c = 0; c < CC; ++c){
        hv[c]  = bf2f(h [base + (size_t)c*NT]);
        g1v[c] = bf2f(g1[base + (size_t)c*NT]);
        g2v[c] = y[base + (size_t)c*NT];
    }
    __syncthreads();
    int lane = tid & 63, wv = tid >> 6;
    for (int o = 0; o < CC; ++o){
        float acc = mlpb[o];
        #pragma unroll
        for (int c = 0; c < CC; ++c){
            acc = fmaf(hv[c],  wl[o*CC + c],        acc);
            acc = fmaf(g1v[c], wl[1024 + o*CC + c], acc);
            acc = fmaf(g2v[c], wl[2048 + o*CC + c], acc);
        }
        y[base + (size_t)o*NT] = acc;
        float s = acc, q = acc*acc;
        for (int off = 32; off; off >>= 1){
            s += __shfl_down(s, off);
            q += __shfl_down(q, off);
        }
        if (lane == 0){ wsum[wv][o] = s; wsq[wv][o] = q; }
    }
    __syncthreads();
    if (tid < CC){
        psum[(size_t)tid*8192 + blk] = wsum[0][tid] + wsum[1][tid] + wsum[2][tid] + wsum[3][tid];
    } else if (tid < 2*CC){
        int o = tid - CC;
        psq[(size_t)o*8192 + blk] = wsq[0][o] + wsq[1][o] + wsq[2][o] + wsq[3][o];
    }
}

// ---------------------------------------------------------------------------
// K5: finalize BN stats -> per-channel scale/shift (deterministic tree)
__global__ void k5_stats(const float* __restrict__ psum, const float* __restrict__ psq,
                         const float* __restrict__ gamma, const float* __restrict__ beta,
                         float* __restrict__ ss){
    int o = blockIdx.x, tid = threadIdx.x;
    double s = 0.0, q = 0.0;
    for (int k = 0; k < 32; ++k){
        s += (double)psum[(size_t)o*8192 + tid + k*256];
        q += (double)psq [(size_t)o*8192 + tid + k*256];
    }
    __shared__ double sd[256], qd[256];
    sd[tid] = s; qd[tid] = q;
    __syncthreads();
    for (int off = 128; off; off >>= 1){
        if (tid < off){ sd[tid] += sd[tid + off]; qd[tid] += qd[tid + off]; }
        __syncthreads();
    }
    if (tid == 0){
        double cnt = (double)BB * NN * TT;
        double mean = sd[0] / cnt;
        double var  = qd[0] / cnt - mean*mean;
        float scale = gamma[o] * (float)(1.0 / sqrt(var + 1e-5));
        float shift = beta[o] - (float)mean * scale;
        ss[o]      = scale;
        ss[CC + o] = shift;
    }
}

// ---------------------------------------------------------------------------
// K6: out = relu(y*scale + shift + res_w@x + res_b), in place on d_out
__global__ __launch_bounds__(256) void k6_final(
    const float* __restrict__ x, const float* __restrict__ rw,
    const float* __restrict__ rb, const float* __restrict__ ss,
    float* __restrict__ y){
    __shared__ float rwl[CC*CC];
    __shared__ float ssl[2*CC];
    int tid = threadIdx.x;
    int blk = blockIdx.x;
    int b = blk >> 9, n = blk & 511;
    for (int idx = tid; idx < CC*CC; idx += 256) rwl[idx] = rw[idx];
    if (tid < 2*CC) ssl[tid] = ss[tid];
    size_t base = (size_t)(b*CC)*NT + (size_t)n*TT + tid;
    float xv[CC];
    #pragma unroll
    for (int c = 0; c < CC; ++c) xv[c] = x[base + (size_t)c*NT];
    __syncthreads();
    for (int o = 0; o < CC; ++o){
        float res = rb[o];
        #pragma unroll
        for (int c = 0; c < CC; ++c) res = fmaf(xv[c], rwl[o*CC + c], res);
        float v = y[base + (size_t)o*NT] * ssl[o] + ssl[CC + o] + res;
        y[base + (size_t)o*NT] = v > 0.0f ? v : 0.0f;
    }
}

// ---------------------------------------------------------------------------
extern "C" void kernel_launch(void* const* d_in, const int* in_sizes, int n_in,
                              void* d_out, int out_size, void* d_ws, size_t ws_size,
                              hipStream_t stream){
    const float* x     = (const float*)d_in[0];
    const float* adj   = (const float*)d_in[1];
    const float* fw    = (const float*)d_in[2];
    const float* fb    = (const float*)d_in[3];
    const float* gw    = (const float*)d_in[4];
    const float* gb    = (const float*)d_in[5];
    const float* mlpw  = (const float*)d_in[6];
    const float* mlpb  = (const float*)d_in[7];
    const float* rw    = (const float*)d_in[8];
    const float* rb    = (const float*)d_in[9];
    const float* gamma = (const float*)d_in[10];
    const float* beta  = (const float*)d_in[11];
    float* out = (float*)d_out;

    char* ws = (char*)d_ws;
    u16*   h_ws  = (u16*)(ws);                                    // 134,217,728 B
    u16*   g1_ws = (u16*)(ws + (size_t)BCNT*2);                   // 134,217,728 B
    u16*   adjb  = (u16*)(ws + (size_t)BCNT*4);                   // 524,288 B
    float* wc    = (float*)(ws + (size_t)BCNT*4 + (size_t)NN*NN*2);            // 12,288 B
    float* ss    = wc + 3072;                                      // 256 B
    float* psum  = ss + 64;                                        // 1 MB
    float* psq   = psum + (size_t)CC*8192;                         // 1 MB

    k0_prep <<<NN, 256, 0, stream>>>(adj, mlpw, adjb, wc);
    k1_gate <<<BB*NN, 256, 0, stream>>>(x, fw, fb, gw, gb, h_ws);
    k2_mfma<0><<<dim3(4, 2, 512), 256, 0, stream>>>(adjb, h_ws, (void*)g1_ws);
    k2_mfma<1><<<dim3(4, 2, 512), 256, 0, stream>>>(adjb, g1_ws, (void*)out);
    k4_mix  <<<BB*NN, 256, 0, stream>>>(h_ws, g1_ws, out, wc, mlpb, psum, psq);
    k5_stats<<<CC, 256, 0, stream>>>(psum, psq, gamma, beta, ss);
    k6_final<<<BB*NN, 256, 0, stream>>>(x, rw, rb, ss, out);
}

// Round 4
// 744.433 us; speedup vs baseline: 3.1289x; 1.7075x over previous
//
#include <hip/hip_runtime.h>
#include <stdint.h>

typedef unsigned short u16;
typedef unsigned int u32;
typedef unsigned long long u64;

#define BB 16
#define CC 32
#define NN 512
#define TT 256
#define NT (NN*TT)            // 131072
#define BCNT (BB*CC*NT)       // 67108864
#define ALPHA 0.05f
#define BETAC 0.95f

typedef __attribute__((ext_vector_type(8))) short short8v;
typedef __attribute__((ext_vector_type(4))) float f32x4;

__device__ __forceinline__ float bf2f(u16 u){ return __uint_as_float(((u32)u) << 16); }
__device__ __forceinline__ u16 f2bf(float f){
    u32 b = __float_as_uint(f);
    u32 r = (b + 0x7FFFu + ((b >> 16) & 1u)) >> 16;
    return (u16)r;
}

// k2-style LDS slot fn (verified round 3): [t(128)][slot(8)] of 16B chunks
__device__ __forceinline__ u32 bslot_addr(int chunk, int t){
    int slot = chunk ^ (t & 7) ^ ((t >> 2) & 7);
    return (u32)((t * 8 + slot) * 16);
}
// fold (chunk 0..3, t 0..255) onto the k2 layout: 16KB per source
__device__ __forceinline__ u32 fold_addr(int chunk, int t){
    int tp = t & 127;
    int cp = chunk + ((t >> 7) << 2);
    int slot = cp ^ (tp & 7) ^ ((tp >> 2) & 7);
    return (u32)((tp * 8 + slot) * 16);
}

// ---------------------------------------------------------------------------
// K0: adj row-normalize -> bf16; bf16 weight prep (combined MLP, filt+gate, res)
__global__ void k0_prep(const float* __restrict__ adj, const float* __restrict__ mlpw,
                        const float* __restrict__ fw, const float* __restrict__ gw,
                        const float* __restrict__ rw,
                        u16* __restrict__ adjb, u16* __restrict__ wcb,
                        u16* __restrict__ fwgb, u16* __restrict__ rwb){
    int i = blockIdx.x;
    int tid = threadIdx.x;
    float a0 = adj[i*NN + tid];
    float a1 = adj[i*NN + tid + 256];
    float s = a0 + a1;
    for (int off = 32; off; off >>= 1) s += __shfl_down(s, off);
    __shared__ float wsum[4];
    if ((tid & 63) == 0) wsum[tid >> 6] = s;
    __syncthreads();
    float inv = 1.0f / (wsum[0] + wsum[1] + wsum[2] + wsum[3] + 1e-8f);
    adjb[i*NN + tid]       = f2bf(a0 * inv);
    adjb[i*NN + tid + 256] = f2bf(a1 * inv);
    if (blockIdx.x == 0){
        for (int idx = tid; idx < 1024; idx += 256){
            int o = idx >> 5, c = idx & 31;
            float m0 = mlpw[o*96 + c];
            float m1 = mlpw[o*96 + 32 + c];
            float m2 = mlpw[o*96 + 64 + c];
            wcb[o*96 + c]      = f2bf(m0 + ALPHA*(m1 + m2));   // Wh
            wcb[o*96 + 32 + c] = f2bf(BETAC*(m1 + ALPHA*m2));  // W1
            wcb[o*96 + 64 + c] = f2bf(BETAC*BETAC*m2);         // W2
        }
        for (int idx = tid; idx < 2048; idx += 256){
            fwgb[idx]        = f2bf(fw[idx]);   // rows 0..31: filt, k-major [o][2c+j]
            fwgb[2048 + idx] = f2bf(gw[idx]);   // rows 32..63: gate
        }
        for (int idx = tid; idx < 1024; idx += 256) rwb[idx] = f2bf(rw[idx]);
    }
}

// ---------------------------------------------------------------------------
// K1 (MFMA): [filt;gate][64][t] = W[64x64] · xpair[64][t] per (b,n); h=tanh*sig
// B built from LDS f32 x-tile (xs[c][t], xs[c][t+1] -> k=2c+j), causal pad xs[c][256]=0
__global__ __launch_bounds__(256) void k1_mfma(
    const float* __restrict__ x, const u16* __restrict__ fwgb,
    const float* __restrict__ fb, const float* __restrict__ gb,
    u16* __restrict__ hOut){
    __shared__ __align__(16) float xs[CC][265];
    __shared__ float fbl[CC], gbl[CC];
    const int tid = threadIdx.x;
    const int lane = tid & 63, w = tid >> 6;
    const int g = lane >> 4, c16 = lane & 15;
    const int n = blockIdx.x, b = blockIdx.y;
    if (tid < CC){ fbl[tid] = fb[tid]; gbl[tid] = gb[tid]; }
    const float* xb = x + (size_t)(b*CC)*NT + (size_t)n*TT;
    {
        int c = tid >> 3, l8 = tid & 7;
        #pragma unroll
        for (int i = 0; i < 8; ++i){
            float4 v = *(const float4*)(xb + (size_t)c*NT + i*32 + l8*4);
            *(float4*)&xs[c][i*32 + l8*4] = v;
        }
        if (tid < CC) xs[tid][256] = 0.0f;   // causal zero-pad
    }
    __syncthreads();
    f32x4 acc[4][4];
    #pragma unroll
    for (int mi = 0; mi < 4; ++mi)
        #pragma unroll
        for (int ni = 0; ni < 4; ++ni) acc[mi][ni] = (f32x4){0.f,0.f,0.f,0.f};
    #pragma unroll
    for (int kc = 0; kc < 2; ++kc){
        short8v bfr[4];
        #pragma unroll
        for (int ni = 0; ni < 4; ++ni){
            int t = w*64 + ni*16 + c16;
            union { u16 e[8]; short8v v; } bu;
            #pragma unroll
            for (int i = 0; i < 4; ++i){
                int c = kc*16 + g*4 + i;
                bu.e[2*i]   = f2bf(xs[c][t]);
                bu.e[2*i+1] = f2bf(xs[c][t+1]);
            }
            bfr[ni] = bu.v;
        }
        short8v a[4];
        #pragma unroll
        for (int mi = 0; mi < 4; ++mi)
            a[mi] = *(const short8v*)(fwgb + (mi*16 + c16)*64 + kc*32 + g*8);
        #pragma unroll
        for (int mi = 0; mi < 4; ++mi)
            #pragma unroll
            for (int ni = 0; ni < 4; ++ni)
                acc[mi][ni] = __builtin_amdgcn_mfma_f32_16x16x32_bf16(
                    a[mi], bfr[ni], acc[mi][ni], 0, 0, 0);
    }
    u16* hb = hOut + (size_t)(b*CC)*NT + (size_t)n*TT;
    #pragma unroll
    for (int mi = 0; mi < 2; ++mi)
        #pragma unroll
        for (int r = 0; r < 4; ++r){
            int o = mi*16 + g*4 + r;
            float fbv = fbl[o], gbv = gbl[o];
            #pragma unroll
            for (int ni = 0; ni < 4; ++ni){
                int t = w*64 + ni*16 + c16;
                float fa = acc[mi][ni][r] + fbv;
                float ga = acc[mi+2][ni][r] + gbv;
                float th = 1.0f - 2.0f / (__expf(2.0f*fa) + 1.0f);
                float sg = 1.0f / (1.0f + __expf(-ga));
                hb[(size_t)o*NT + t] = f2bf(th * sg);
            }
        }
}

// ---------------------------------------------------------------------------
// K2 (MFMA, unchanged from passing round 3): dst[bc][i][t] = sum_j adjb[i][j]*src[bc][j][t]
template<int DSTF32>
__global__ __launch_bounds__(256) void k2_mfma(
    const u16* __restrict__ adjb, const u16* __restrict__ src, void* __restrict__ dst){
    __shared__ __align__(16) u16 Bl[128*64];
    const int tid = threadIdx.x;
    const int lane = tid & 63, w = tid >> 6;
    const int wm = w >> 1, wn = w & 1;
    const int g = lane >> 4, c16 = lane & 15;
    const int i0 = blockIdx.x * 128;
    const int t0 = blockIdx.y * 128;
    const int bc = blockIdx.z;
    const u16* srcb = src + (size_t)bc * NT;
    const int s_chunk = tid >> 5;
    const int s_tb    = (tid & 31) * 4;
    f32x4 acc[4][4];
    #pragma unroll
    for (int mi = 0; mi < 4; ++mi)
        #pragma unroll
        for (int ni = 0; ni < 4; ++ni) acc[mi][ni] = (f32x4){0.f,0.f,0.f,0.f};
    const u16* arow[4];
    #pragma unroll
    for (int mi = 0; mi < 4; ++mi)
        arow[mi] = adjb + (size_t)(i0 + wm*64 + mi*16 + c16) * NN;
    for (int step = 0; step < 8; ++step){
        const int k0 = step * 64;
        uint2 v[8];
        #pragma unroll
        for (int r = 0; r < 8; ++r)
            v[r] = *(const uint2*)(srcb + (size_t)(k0 + s_chunk*8 + r)*TT + t0 + s_tb);
        __syncthreads();
        #pragma unroll
        for (int j = 0; j < 4; ++j){
            u32 d[4];
            #pragma unroll
            for (int p = 0; p < 4; ++p){
                u32 lo = (j < 2) ? v[2*p].x   : v[2*p].y;
                u32 hi = (j < 2) ? v[2*p+1].x : v[2*p+1].y;
                u32 sh = (j & 1) * 16;
                d[p] = ((lo >> sh) & 0xFFFFu) | (((hi >> sh) & 0xFFFFu) << 16);
            }
            uint4 q = {d[0], d[1], d[2], d[3]};
            *(uint4*)((char*)Bl + bslot_addr(s_chunk, s_tb + j)) = q;
        }
        __syncthreads();
        #pragma unroll
        for (int kc = 0; kc < 2; ++kc){
            short8v a[4];
            #pragma unroll
            for (int mi = 0; mi < 4; ++mi)
                a[mi] = *(const short8v*)(arow[mi] + k0 + kc*32 + g*8);
            short8v bfr[4];
            #pragma unroll
            for (int ni = 0; ni < 4; ++ni){
                int t_loc = wn*64 + ni*16 + c16;
                bfr[ni] = *(const short8v*)((const char*)Bl + bslot_addr(kc*4 + g, t_loc));
            }
            #pragma unroll
            for (int mi = 0; mi < 4; ++mi)
                #pragma unroll
                for (int ni = 0; ni < 4; ++ni)
                    acc[mi][ni] = __builtin_amdgcn_mfma_f32_16x16x32_bf16(
                        a[mi], bfr[ni], acc[mi][ni], 0, 0, 0);
        }
    }
    if (DSTF32){
        float* d = (float*)dst + (size_t)bc * NT;
        #pragma unroll
        for (int mi = 0; mi < 4; ++mi)
            #pragma unroll
            for (int ni = 0; ni < 4; ++ni){
                int tt = t0 + wn*64 + ni*16 + c16;
                int ib = i0 + wm*64 + mi*16 + g*4;
                #pragma unroll
                for (int r = 0; r < 4; ++r)
                    d[(size_t)(ib + r)*TT + tt] = acc[mi][ni][r];
            }
    } else {
        u16* d = (u16*)dst + (size_t)bc * NT;
        #pragma unroll
        for (int mi = 0; mi < 4; ++mi)
            #pragma unroll
            for (int ni = 0; ni < 4; ++ni){
                int tt = t0 + wn*64 + ni*16 + c16;
                int ib = i0 + wm*64 + mi*16 + g*4;
                #pragma unroll
                for (int r = 0; r < 4; ++r)
                    d[(size_t)(ib + r)*TT + tt] = f2bf(acc[mi][ni][r]);
            }
    }
}

// ---------------------------------------------------------------------------
// K4 (MFMA): y_pre[32][t] = Wc[32x96]·[h;g1;g2][96][t] + mlp_b per (b, 256-nt tile)
// y_pre -> bf16 IN-PLACE into h_ws; per-block BN partials (deterministic)
__global__ __launch_bounds__(256) void k4_mfma(
    const u16* __restrict__ h, const u16* __restrict__ g1, const u16* __restrict__ g2,
    const u16* __restrict__ wcb, const float* __restrict__ mlpb,
    u16* __restrict__ ypre, float* __restrict__ psum, float* __restrict__ psq){
    __shared__ __align__(16) u16 Bt[3*8192];       // 48 KB
    __shared__ float mbl[CC];
    __shared__ float part[2][4][CC];
    const int tid = threadIdx.x;
    const int lane = tid & 63, w = tid >> 6;
    const int g = lane >> 4, c16 = lane & 15;
    const int nt0 = blockIdx.x * 256;
    const int b = blockIdx.y;
    const int blk = b * 512 + blockIdx.x;
    if (tid < CC) mbl[tid] = mlpb[tid];
    const size_t boff = (size_t)(b*CC)*NT;
    const u16* srcs[3] = { h + boff, g1 + boff, g2 + boff };
    const int chunk = w, tq = lane;
    #pragma unroll
    for (int s = 0; s < 3; ++s){
        uint2 v[8];
        #pragma unroll
        for (int r = 0; r < 8; ++r)
            v[r] = *(const uint2*)(srcs[s] + (size_t)(chunk*8 + r)*NT + nt0 + tq*4);
        #pragma unroll
        for (int j = 0; j < 4; ++j){
            u32 d[4];
            #pragma unroll
            for (int p = 0; p < 4; ++p){
                u32 lo = (j < 2) ? v[2*p].x   : v[2*p].y;
                u32 hi = (j < 2) ? v[2*p+1].x : v[2*p+1].y;
                u32 sh = (j & 1) * 16;
                d[p] = ((lo >> sh) & 0xFFFFu) | (((hi >> sh) & 0xFFFFu) << 16);
            }
            uint4 q = {d[0], d[1], d[2], d[3]};
            *(uint4*)((char*)Bt + s*16384 + fold_addr(chunk, tq*4 + j)) = q;
        }
    }
    short8v a[3][2];
    #pragma unroll
    for (int s = 0; s < 3; ++s)
        #pragma unroll
        for (int mi = 0; mi < 2; ++mi)
            a[s][mi] = *(const short8v*)(wcb + (mi*16 + c16)*96 + s*32 + g*8);
    f32x4 acc[2][4];
    #pragma unroll
    for (int mi = 0; mi < 2; ++mi)
        #pragma unroll
        for (int ni = 0; ni < 4; ++ni) acc[mi][ni] = (f32x4){0.f,0.f,0.f,0.f};
    __syncthreads();
    #pragma unroll
    for (int s = 0; s < 3; ++s){
        short8v bfr[4];
        #pragma unroll
        for (int ni = 0; ni < 4; ++ni){
            int t = w*64 + ni*16 + c16;
            bfr[ni] = *(const short8v*)((const char*)Bt + s*16384 + fold_addr(g, t));
        }
        #pragma unroll
        for (int mi = 0; mi < 2; ++mi)
            #pragma unroll
            for (int ni = 0; ni < 4; ++ni)
                acc[mi][ni] = __builtin_amdgcn_mfma_f32_16x16x32_bf16(
                    a[s][mi], bfr[ni], acc[mi][ni], 0, 0, 0);
    }
    // epilogue: bias, bf16 store into h_ws window, BN partials
    u16* yb = ypre + boff;
    #pragma unroll
    for (int mi = 0; mi < 2; ++mi)
        #pragma unroll
        for (int r = 0; r < 4; ++r){
            int o = mi*16 + g*4 + r;
            float bias = mbl[o];
            float sv = 0.f, qv = 0.f;
            #pragma unroll
            for (int ni = 0; ni < 4; ++ni){
                int t = nt0 + w*64 + ni*16 + c16;
                float y = acc[mi][ni][r] + bias;
                yb[(size_t)o*NT + t] = f2bf(y);
                sv += y; qv += y*y;
            }
            #pragma unroll
            for (int m = 1; m < 16; m <<= 1){
                sv += __shfl_xor(sv, m);
                qv += __shfl_xor(qv, m);
            }
            if (c16 == 0){ part[0][w][o] = sv; part[1][w][o] = qv; }
        }
    __syncthreads();
    if (tid < CC){
        psum[(size_t)tid*8192 + blk] = part[0][0][tid] + part[0][1][tid] + part[0][2][tid] + part[0][3][tid];
    } else if (tid < 2*CC){
        int o = tid - CC;
        psq[(size_t)o*8192 + blk] = part[1][0][o] + part[1][1][o] + part[1][2][o] + part[1][3][o];
    }
}

// ---------------------------------------------------------------------------
// K5: finalize BN stats -> per-channel scale/shift (deterministic tree)
__global__ void k5_stats(const float* __restrict__ psum, const float* __restrict__ psq,
                         const float* __restrict__ gamma, const float* __restrict__ beta,
                         float* __restrict__ ss){
    int o = blockIdx.x, tid = threadIdx.x;
    double s = 0.0, q = 0.0;
    for (int k = 0; k < 32; ++k){
        s += (double)psum[(size_t)o*8192 + tid + k*256];
        q += (double)psq [(size_t)o*8192 + tid + k*256];
    }
    __shared__ double sd[256], qd[256];
    sd[tid] = s; qd[tid] = q;
    __syncthreads();
    for (int off = 128; off; off >>= 1){
        if (tid < off){ sd[tid] += sd[tid + off]; qd[tid] += qd[tid + off]; }
        __syncthreads();
    }
    if (tid == 0){
        double cnt = (double)BB * NN * TT;
        double mean = sd[0] / cnt;
        double var  = qd[0] / cnt - mean*mean;
        float scale = gamma[o] * (float)(1.0 / sqrt(var + 1e-5));
        float shift = beta[o] - (float)mean * scale;
        ss[o]      = scale;
        ss[CC + o] = shift;
    }
}

// ---------------------------------------------------------------------------
// K6 (MFMA): res[32][t] = rwb[32x32]·x[32][t]; out = relu(res + rb + scale*ypre + shift)
__global__ __launch_bounds__(256) void k6_mfma(
    const float* __restrict__ x, const u16* __restrict__ rwb,
    const float* __restrict__ rb, const float* __restrict__ ss,
    const u16* __restrict__ ypre, float* __restrict__ out){
    __shared__ __align__(16) u16 Bt[8192];   // 16 KB
    __shared__ float rbl[CC], ssl[2*CC];
    const int tid = threadIdx.x;
    const int lane = tid & 63, w = tid >> 6;
    const int g = lane >> 4, c16 = lane & 15;
    const int nt0 = blockIdx.x * 256;
    const int b = blockIdx.y;
    if (tid < CC) rbl[tid] = rb[tid];
    if (tid < 2*CC) ssl[tid] = ss[tid];
    const size_t boff = (size_t)(b*CC)*NT;
    const float* xb = x + boff;
    const int chunk = w, tq = lane;
    {
        float vv[8][4];
        #pragma unroll
        for (int r = 0; r < 8; ++r){
            float4 v = *(const float4*)(xb + (size_t)(chunk*8 + r)*NT + nt0 + tq*4);
            vv[r][0] = v.x; vv[r][1] = v.y; vv[r][2] = v.z; vv[r][3] = v.w;
        }
        #pragma unroll
        for (int j = 0; j < 4; ++j){
            u32 d[4];
            #pragma unroll
            for (int p = 0; p < 4; ++p)
                d[p] = (u32)f2bf(vv[2*p][j]) | ((u32)f2bf(vv[2*p+1][j]) << 16);
            uint4 q = {d[0], d[1], d[2], d[3]};
            *(uint4*)((char*)Bt + fold_addr(chunk, tq*4 + j)) = q;
        }
    }
    short8v a[2];
    #pragma unroll
    for (int mi = 0; mi < 2; ++mi)
        a[mi] = *(const short8v*)(rwb + (mi*16 + c16)*32 + g*8);
    f32x4 acc[2][4];
    #pragma unroll
    for (int mi = 0; mi < 2; ++mi)
        #pragma unroll
        for (int ni = 0; ni < 4; ++ni) acc[mi][ni] = (f32x4){0.f,0.f,0.f,0.f};
    __syncthreads();
    {
        short8v bfr[4];
        #pragma unroll
        for (int ni = 0; ni < 4; ++ni){
            int t = w*64 + ni*16 + c16;
            bfr[ni] = *(const short8v*)((const char*)Bt + fold_addr(g, t));
        }
        #pragma unroll
        for (int mi = 0; mi < 2; ++mi)
            #pragma unroll
            for (int ni = 0; ni < 4; ++ni)
                acc[mi][ni] = __builtin_amdgcn_mfma_f32_16x16x32_bf16(
                    a[mi], bfr[ni], acc[mi][ni], 0, 0, 0);
    }
    const u16* yb = ypre + boff;
    float* ob = out + boff;
    #pragma unroll
    for (int mi = 0; mi < 2; ++mi)
        #pragma unroll
        for (int r = 0; r < 4; ++r){
            int o = mi*16 + g*4 + r;
            float sc = ssl[o], sh = ssl[CC + o], rbv = rbl[o];
            #pragma unroll
            for (int ni = 0; ni < 4; ++ni){
                int t = nt0 + w*64 + ni*16 + c16;
                float v = acc[mi][ni][r] + rbv + sc * bf2f(yb[(size_t)o*NT + t]) + sh;
                ob[(size_t)o*NT + t] = v > 0.0f ? v : 0.0f;
            }
        }
}

// ---------------------------------------------------------------------------
extern "C" void kernel_launch(void* const* d_in, const int* in_sizes, int n_in,
                              void* d_out, int out_size, void* d_ws, size_t ws_size,
                              hipStream_t stream){
    const float* x     = (const float*)d_in[0];
    const float* adj   = (const float*)d_in[1];
    const float* fw    = (const float*)d_in[2];
    const float* fb    = (const float*)d_in[3];
    const float* gw    = (const float*)d_in[4];
    const float* gb    = (const float*)d_in[5];
    const float* mlpw  = (const float*)d_in[6];
    const float* mlpb  = (const float*)d_in[7];
    const float* rw    = (const float*)d_in[8];
    const float* rb    = (const float*)d_in[9];
    const float* gamma = (const float*)d_in[10];
    const float* beta  = (const float*)d_in[11];
    float* out = (float*)d_out;

    char* ws = (char*)d_ws;
    u16*   h_ws  = (u16*)(ws);                          // 134,217,728 B (h, then y_pre in place)
    u16*   g1_ws = (u16*)(ws + (size_t)BCNT*2);         // 134,217,728 B
    char*  p     = ws + (size_t)BCNT*4;
    u16*   adjb  = (u16*)p;            p += (size_t)NN*NN*2;   // 524,288 B
    u16*   wcb   = (u16*)p;            p += 3072*2;            // 6,144 B
    u16*   fwgb  = (u16*)p;            p += 4096*2;            // 8,192 B
    u16*   rwb   = (u16*)p;            p += 1024*2;            // 2,048 B
    float* ssb   = (float*)p;          p += 64*4;              // 256 B
    float* psum  = (float*)p;          p += (size_t)CC*8192*4; // 1 MB
    float* psq   = (float*)p;                                  // 1 MB
    u16*   g2b   = (u16*)d_out;        // g2 bf16 staged in d_out, consumed by k4

    k0_prep <<<NN, 256, 0, stream>>>(adj, mlpw, fw, gw, rw, adjb, wcb, fwgb, rwb);
    k1_mfma <<<dim3(NN, BB), 256, 0, stream>>>(x, fwgb, fb, gb, h_ws);
    k2_mfma<0><<<dim3(4, 2, 512), 256, 0, stream>>>(adjb, h_ws, (void*)g1_ws);
    k2_mfma<0><<<dim3(4, 2, 512), 256, 0, stream>>>(adjb, g1_ws, (void*)g2b);
    k4_mfma <<<dim3(512, BB), 256, 0, stream>>>(h_ws, g1_ws, g2b, wcb, mlpb,
                                                h_ws, psum, psq);
    k5_stats<<<CC, 256, 0, stream>>>(psum, psq, gamma, beta, ssb);
    k6_mfma <<<dim3(512, BB), 256, 0, stream>>>(x, rwb, rb, ssb, h_ws, out);
}

// Round 5
// 733.199 us; speedup vs baseline: 3.1769x; 1.0153x over previous
//
#include <hip/hip_runtime.h>
#include <stdint.h>

typedef unsigned short u16;
typedef unsigned int u32;
typedef unsigned long long u64;

#define BB 16
#define CC 32
#define NN 512
#define TT 256
#define NT (NN*TT)            // 131072
#define BCNT (BB*CC*NT)       // 67108864
#define ALPHA 0.05f
#define BETAC 0.95f

typedef __attribute__((ext_vector_type(8))) short short8v;
typedef __attribute__((ext_vector_type(4))) float f32x4;

__device__ __forceinline__ float bf2f(u16 u){ return __uint_as_float(((u32)u) << 16); }
__device__ __forceinline__ u16 f2bf(float f){
    u32 b = __float_as_uint(f);
    u32 r = (b + 0x7FFFu + ((b >> 16) & 1u)) >> 16;
    return (u16)r;
}

// k2-style LDS slot fn (verified round 3): [t(128)][slot(8)] of 16B chunks
__device__ __forceinline__ u32 bslot_addr(int chunk, int t){
    int slot = chunk ^ (t & 7) ^ ((t >> 2) & 7);
    return (u32)((t * 8 + slot) * 16);
}
// fold (chunk 0..3, t 0..255) onto the k2 layout: 16KB per source
__device__ __forceinline__ u32 fold_addr(int chunk, int t){
    int tp = t & 127;
    int cp = chunk + ((t >> 7) << 2);
    int slot = cp ^ (tp & 7) ^ ((tp >> 2) & 7);
    return (u32)((tp * 8 + slot) * 16);
}

// ---------------------------------------------------------------------------
// K0: adj row-normalize -> bf16; bf16 weight prep (combined MLP, filt+gate, res)
__global__ void k0_prep(const float* __restrict__ adj, const float* __restrict__ mlpw,
                        const float* __restrict__ fw, const float* __restrict__ gw,
                        const float* __restrict__ rw,
                        u16* __restrict__ adjb, u16* __restrict__ wcb,
                        u16* __restrict__ fwgb, u16* __restrict__ rwb){
    int i = blockIdx.x;
    int tid = threadIdx.x;
    float a0 = adj[i*NN + tid];
    float a1 = adj[i*NN + tid + 256];
    float s = a0 + a1;
    for (int off = 32; off; off >>= 1) s += __shfl_down(s, off);
    __shared__ float wsum[4];
    if ((tid & 63) == 0) wsum[tid >> 6] = s;
    __syncthreads();
    float inv = 1.0f / (wsum[0] + wsum[1] + wsum[2] + wsum[3] + 1e-8f);
    adjb[i*NN + tid]       = f2bf(a0 * inv);
    adjb[i*NN + tid + 256] = f2bf(a1 * inv);
    if (blockIdx.x == 0){
        for (int idx = tid; idx < 1024; idx += 256){
            int o = idx >> 5, c = idx & 31;
            float m0 = mlpw[o*96 + c];
            float m1 = mlpw[o*96 + 32 + c];
            float m2 = mlpw[o*96 + 64 + c];
            wcb[o*96 + c]      = f2bf(m0 + ALPHA*(m1 + m2));   // Wh
            wcb[o*96 + 32 + c] = f2bf(BETAC*(m1 + ALPHA*m2));  // W1
            wcb[o*96 + 64 + c] = f2bf(BETAC*BETAC*m2);         // W2
        }
        for (int idx = tid; idx < 2048; idx += 256){
            fwgb[idx]        = f2bf(fw[idx]);   // rows 0..31: filt, k-major [o][2c+j]
            fwgb[2048 + idx] = f2bf(gw[idx]);   // rows 32..63: gate
        }
        for (int idx = tid; idx < 1024; idx += 256) rwb[idx] = f2bf(rw[idx]);
    }
}

// ---------------------------------------------------------------------------
// K1 (MFMA): [filt;gate][64][t] = W[64x64] · xpair[64][t] per (b,n); h=tanh*sig
__global__ __launch_bounds__(256) void k1_mfma(
    const float* __restrict__ x, const u16* __restrict__ fwgb,
    const float* __restrict__ fb, const float* __restrict__ gb,
    u16* __restrict__ hOut){
    __shared__ __align__(16) float xs[CC][265];
    __shared__ float fbl[CC], gbl[CC];
    const int tid = threadIdx.x;
    const int lane = tid & 63, w = tid >> 6;
    const int g = lane >> 4, c16 = lane & 15;
    const int n = blockIdx.x, b = blockIdx.y;
    if (tid < CC){ fbl[tid] = fb[tid]; gbl[tid] = gb[tid]; }
    const float* xb = x + (size_t)(b*CC)*NT + (size_t)n*TT;
    {
        int c = tid >> 3, l8 = tid & 7;
        #pragma unroll
        for (int i = 0; i < 8; ++i){
            float4 v = *(const float4*)(xb + (size_t)c*NT + i*32 + l8*4);
            *(float4*)&xs[c][i*32 + l8*4] = v;
        }
        if (tid < CC) xs[tid][256] = 0.0f;   // causal zero-pad
    }
    __syncthreads();
    f32x4 acc[4][4];
    #pragma unroll
    for (int mi = 0; mi < 4; ++mi)
        #pragma unroll
        for (int ni = 0; ni < 4; ++ni) acc[mi][ni] = (f32x4){0.f,0.f,0.f,0.f};
    #pragma unroll
    for (int kc = 0; kc < 2; ++kc){
        short8v bfr[4];
        #pragma unroll
        for (int ni = 0; ni < 4; ++ni){
            int t = w*64 + ni*16 + c16;
            union { u16 e[8]; short8v v; } bu;
            #pragma unroll
            for (int i = 0; i < 4; ++i){
                int c = kc*16 + g*4 + i;
                bu.e[2*i]   = f2bf(xs[c][t]);
                bu.e[2*i+1] = f2bf(xs[c][t+1]);
            }
            bfr[ni] = bu.v;
        }
        short8v a[4];
        #pragma unroll
        for (int mi = 0; mi < 4; ++mi)
            a[mi] = *(const short8v*)(fwgb + (mi*16 + c16)*64 + kc*32 + g*8);
        #pragma unroll
        for (int mi = 0; mi < 4; ++mi)
            #pragma unroll
            for (int ni = 0; ni < 4; ++ni)
                acc[mi][ni] = __builtin_amdgcn_mfma_f32_16x16x32_bf16(
                    a[mi], bfr[ni], acc[mi][ni], 0, 0, 0);
    }
    u16* hb = hOut + (size_t)(b*CC)*NT + (size_t)n*TT;
    #pragma unroll
    for (int mi = 0; mi < 2; ++mi)
        #pragma unroll
        for (int r = 0; r < 4; ++r){
            int o = mi*16 + g*4 + r;
            float fbv = fbl[o], gbv = gbl[o];
            #pragma unroll
            for (int ni = 0; ni < 4; ++ni){
                int t = w*64 + ni*16 + c16;
                float fa = acc[mi][ni][r] + fbv;
                float ga = acc[mi+2][ni][r] + gbv;
                float th = 1.0f - 2.0f / (__expf(2.0f*fa) + 1.0f);
                float sg = 1.0f / (1.0f + __expf(-ga));
                hb[(size_t)o*NT + t] = f2bf(th * sg);
            }
        }
}

// ---------------------------------------------------------------------------
// K2 (MFMA): dst[bc][i][t] = sum_j adjb[i][j]*src[bc][j][t]
// Round-5: LDS double-buffer + loads issued one step ahead (latency hidden
// under compute), one barrier per step; XCD-contiguous work swizzle so the
// 8 blocks of one bc run on one XCD (L2 reuse of src).
template<int DSTF32>
__global__ __launch_bounds__(256) void k2_mfma(
    const u16* __restrict__ adjb, const u16* __restrict__ src, void* __restrict__ dst){
    __shared__ __align__(16) u16 Bl[2][128*64];   // 2 x 16 KB
    const int tid = threadIdx.x;
    const int lane = tid & 63, w = tid >> 6;
    const int wm = w >> 1, wn = w & 1;
    const int g = lane >> 4, c16 = lane & 15;
    // XCD-contiguous mapping: flat%8 = XCD (round-robin assumption); each XCD
    // gets a contiguous range of 512 work items = 64 whole bc's.
    const u32 flat = blockIdx.x;                  // 0..4095
    const u32 work = (flat & 7u) * 512u + (flat >> 3);
    const int bc = (int)(work >> 3);
    const int sub = (int)(work & 7u);
    const int i0 = (sub >> 1) * 128;
    const int t0 = (sub & 1) * 128;
    const u16* srcb = src + (size_t)bc * NT;
    const int s_chunk = tid >> 5;
    const int s_tb    = (tid & 31) * 4;
    f32x4 acc[4][4];
    #pragma unroll
    for (int mi = 0; mi < 4; ++mi)
        #pragma unroll
        for (int ni = 0; ni < 4; ++ni) acc[mi][ni] = (f32x4){0.f,0.f,0.f,0.f};
    const u16* arow[4];
    #pragma unroll
    for (int mi = 0; mi < 4; ++mi)
        arow[mi] = adjb + (size_t)(i0 + wm*64 + mi*16 + c16) * NN;

    // prologue: load step 0
    uint2 v[8];
    #pragma unroll
    for (int r = 0; r < 8; ++r)
        v[r] = *(const uint2*)(srcb + (size_t)(s_chunk*8 + r)*TT + t0 + s_tb);

    for (int step = 0; step < 8; ++step){
        const int k0 = step * 64;
        char* bbase = (char*)Bl + (size_t)(step & 1) * 16384;
        // ---- repack current step's registers into LDS buf[cur] ----
        #pragma unroll
        for (int j = 0; j < 4; ++j){
            u32 d[4];
            #pragma unroll
            for (int p = 0; p < 4; ++p){
                u32 lo = (j < 2) ? v[2*p].x   : v[2*p].y;
                u32 hi = (j < 2) ? v[2*p+1].x : v[2*p+1].y;
                u32 sh = (j & 1) * 16;
                d[p] = ((lo >> sh) & 0xFFFFu) | (((hi >> sh) & 0xFFFFu) << 16);
            }
            uint4 q = {d[0], d[1], d[2], d[3]};
            *(uint4*)(bbase + bslot_addr(s_chunk, s_tb + j)) = q;
        }
        // ---- issue next step's global loads (latency hides under compute) ----
        if (step < 7){
            const int k0n = k0 + 64;
            #pragma unroll
            for (int r = 0; r < 8; ++r)
                v[r] = *(const uint2*)(srcb + (size_t)(k0n + s_chunk*8 + r)*TT + t0 + s_tb);
        }
        __syncthreads();
        // ---- compute from buf[cur] ----
        #pragma unroll
        for (int kc = 0; kc < 2; ++kc){
            short8v a[4];
            #pragma unroll
            for (int mi = 0; mi < 4; ++mi)
                a[mi] = *(const short8v*)(arow[mi] + k0 + kc*32 + g*8);
            short8v bfr[4];
            #pragma unroll
            for (int ni = 0; ni < 4; ++ni){
                int t_loc = wn*64 + ni*16 + c16;
                bfr[ni] = *(const short8v*)(bbase + bslot_addr(kc*4 + g, t_loc));
            }
            #pragma unroll
            for (int mi = 0; mi < 4; ++mi)
                #pragma unroll
                for (int ni = 0; ni < 4; ++ni)
                    acc[mi][ni] = __builtin_amdgcn_mfma_f32_16x16x32_bf16(
                        a[mi], bfr[ni], acc[mi][ni], 0, 0, 0);
        }
    }
    if (DSTF32){
        float* d = (float*)dst + (size_t)bc * NT;
        #pragma unroll
        for (int mi = 0; mi < 4; ++mi)
            #pragma unroll
            for (int ni = 0; ni < 4; ++ni){
                int tt = t0 + wn*64 + ni*16 + c16;
                int ib = i0 + wm*64 + mi*16 + g*4;
                #pragma unroll
                for (int r = 0; r < 4; ++r)
                    d[(size_t)(ib + r)*TT + tt] = acc[mi][ni][r];
            }
    } else {
        u16* d = (u16*)dst + (size_t)bc * NT;
        #pragma unroll
        for (int mi = 0; mi < 4; ++mi)
            #pragma unroll
            for (int ni = 0; ni < 4; ++ni){
                int tt = t0 + wn*64 + ni*16 + c16;
                int ib = i0 + wm*64 + mi*16 + g*4;
                #pragma unroll
                for (int r = 0; r < 4; ++r)
                    d[(size_t)(ib + r)*TT + tt] = f2bf(acc[mi][ni][r]);
            }
    }
}

// ---------------------------------------------------------------------------
// K4 (MFMA): y_pre[32][t] = Wc[32x96]·[h;g1;g2][96][t] + mlp_b per (b, 256-nt tile)
__global__ __launch_bounds__(256) void k4_mfma(
    const u16* __restrict__ h, const u16* __restrict__ g1, const u16* __restrict__ g2,
    const u16* __restrict__ wcb, const float* __restrict__ mlpb,
    u16* __restrict__ ypre, float* __restrict__ psum, float* __restrict__ psq){
    __shared__ __align__(16) u16 Bt[3*8192];       // 48 KB
    __shared__ float mbl[CC];
    __shared__ float part[2][4][CC];
    const int tid = threadIdx.x;
    const int lane = tid & 63, w = tid >> 6;
    const int g = lane >> 4, c16 = lane & 15;
    const int nt0 = blockIdx.x * 256;
    const int b = blockIdx.y;
    const int blk = b * 512 + blockIdx.x;
    if (tid < CC) mbl[tid] = mlpb[tid];
    const size_t boff = (size_t)(b*CC)*NT;
    const u16* srcs[3] = { h + boff, g1 + boff, g2 + boff };
    const int chunk = w, tq = lane;
    #pragma unroll
    for (int s = 0; s < 3; ++s){
        uint2 v[8];
        #pragma unroll
        for (int r = 0; r < 8; ++r)
            v[r] = *(const uint2*)(srcs[s] + (size_t)(chunk*8 + r)*NT + nt0 + tq*4);
        #pragma unroll
        for (int j = 0; j < 4; ++j){
            u32 d[4];
            #pragma unroll
            for (int p = 0; p < 4; ++p){
                u32 lo = (j < 2) ? v[2*p].x   : v[2*p].y;
                u32 hi = (j < 2) ? v[2*p+1].x : v[2*p+1].y;
                u32 sh = (j & 1) * 16;
                d[p] = ((lo >> sh) & 0xFFFFu) | (((hi >> sh) & 0xFFFFu) << 16);
            }
            uint4 q = {d[0], d[1], d[2], d[3]};
            *(uint4*)((char*)Bt + s*16384 + fold_addr(chunk, tq*4 + j)) = q;
        }
    }
    short8v a[3][2];
    #pragma unroll
    for (int s = 0; s < 3; ++s)
        #pragma unroll
        for (int mi = 0; mi < 2; ++mi)
            a[s][mi] = *(const short8v*)(wcb + (mi*16 + c16)*96 + s*32 + g*8);
    f32x4 acc[2][4];
    #pragma unroll
    for (int mi = 0; mi < 2; ++mi)
        #pragma unroll
        for (int ni = 0; ni < 4; ++ni) acc[mi][ni] = (f32x4){0.f,0.f,0.f,0.f};
    __syncthreads();
    #pragma unroll
    for (int s = 0; s < 3; ++s){
        short8v bfr[4];
        #pragma unroll
        for (int ni = 0; ni < 4; ++ni){
            int t = w*64 + ni*16 + c16;
            bfr[ni] = *(const short8v*)((const char*)Bt + s*16384 + fold_addr(g, t));
        }
        #pragma unroll
        for (int mi = 0; mi < 2; ++mi)
            #pragma unroll
            for (int ni = 0; ni < 4; ++ni)
                acc[mi][ni] = __builtin_amdgcn_mfma_f32_16x16x32_bf16(
                    a[s][mi], bfr[ni], acc[mi][ni], 0, 0, 0);
    }
    u16* yb = ypre + boff;
    #pragma unroll
    for (int mi = 0; mi < 2; ++mi)
        #pragma unroll
        for (int r = 0; r < 4; ++r){
            int o = mi*16 + g*4 + r;
            float bias = mbl[o];
            float sv = 0.f, qv = 0.f;
            #pragma unroll
            for (int ni = 0; ni < 4; ++ni){
                int t = nt0 + w*64 + ni*16 + c16;
                float y = acc[mi][ni][r] + bias;
                yb[(size_t)o*NT + t] = f2bf(y);
                sv += y; qv += y*y;
            }
            #pragma unroll
            for (int m = 1; m < 16; m <<= 1){
                sv += __shfl_xor(sv, m);
                qv += __shfl_xor(qv, m);
            }
            if (c16 == 0){ part[0][w][o] = sv; part[1][w][o] = qv; }
        }
    __syncthreads();
    if (tid < CC){
        psum[(size_t)tid*8192 + blk] = part[0][0][tid] + part[0][1][tid] + part[0][2][tid] + part[0][3][tid];
    } else if (tid < 2*CC){
        int o = tid - CC;
        psq[(size_t)o*8192 + blk] = part[1][0][o] + part[1][1][o] + part[1][2][o] + part[1][3][o];
    }
}

// ---------------------------------------------------------------------------
// K5: finalize BN stats -> per-channel scale/shift (deterministic tree)
__global__ void k5_stats(const float* __restrict__ psum, const float* __restrict__ psq,
                         const float* __restrict__ gamma, const float* __restrict__ beta,
                         float* __restrict__ ss){
    int o = blockIdx.x, tid = threadIdx.x;
    double s = 0.0, q = 0.0;
    for (int k = 0; k < 32; ++k){
        s += (double)psum[(size_t)o*8192 + tid + k*256];
        q += (double)psq [(size_t)o*8192 + tid + k*256];
    }
    __shared__ double sd[256], qd[256];
    sd[tid] = s; qd[tid] = q;
    __syncthreads();
    for (int off = 128; off; off >>= 1){
        if (tid < off){ sd[tid] += sd[tid + off]; qd[tid] += qd[tid + off]; }
        __syncthreads();
    }
    if (tid == 0){
        double cnt = (double)BB * NN * TT;
        double mean = sd[0] / cnt;
        double var  = qd[0] / cnt - mean*mean;
        float scale = gamma[o] * (float)(1.0 / sqrt(var + 1e-5));
        float shift = beta[o] - (float)mean * scale;
        ss[o]      = scale;
        ss[CC + o] = shift;
    }
}

// ---------------------------------------------------------------------------
// K6 (MFMA): res[32][t] = rwb[32x32]·x[32][t]; out = relu(res + rb + scale*ypre + shift)
__global__ __launch_bounds__(256) void k6_mfma(
    const float* __restrict__ x, const u16* __restrict__ rwb,
    const float* __restrict__ rb, const float* __restrict__ ss,
    const u16* __restrict__ ypre, float* __restrict__ out){
    __shared__ __align__(16) u16 Bt[8192];   // 16 KB
    __shared__ float rbl[CC], ssl[2*CC];
    const int tid = threadIdx.x;
    const int lane = tid & 63, w = tid >> 6;
    const int g = lane >> 4, c16 = lane & 15;
    const int nt0 = blockIdx.x * 256;
    const int b = blockIdx.y;
    if (tid < CC) rbl[tid] = rb[tid];
    if (tid < 2*CC) ssl[tid] = ss[tid];
    const size_t boff = (size_t)(b*CC)*NT;
    const float* xb = x + boff;
    const int chunk = w, tq = lane;
    {
        float vv[8][4];
        #pragma unroll
        for (int r = 0; r < 8; ++r){
            float4 v = *(const float4*)(xb + (size_t)(chunk*8 + r)*NT + nt0 + tq*4);
            vv[r][0] = v.x; vv[r][1] = v.y; vv[r][2] = v.z; vv[r][3] = v.w;
        }
        #pragma unroll
        for (int j = 0; j < 4; ++j){
            u32 d[4];
            #pragma unroll
            for (int p = 0; p < 4; ++p)
                d[p] = (u32)f2bf(vv[2*p][j]) | ((u32)f2bf(vv[2*p+1][j]) << 16);
            uint4 q = {d[0], d[1], d[2], d[3]};
            *(uint4*)((char*)Bt + fold_addr(chunk, tq*4 + j)) = q;
        }
    }
    short8v a[2];
    #pragma unroll
    for (int mi = 0; mi < 2; ++mi)
        a[mi] = *(const short8v*)(rwb + (mi*16 + c16)*32 + g*8);
    f32x4 acc[2][4];
    #pragma unroll
    for (int mi = 0; mi < 2; ++mi)
        #pragma unroll
        for (int ni = 0; ni < 4; ++ni) acc[mi][ni] = (f32x4){0.f,0.f,0.f,0.f};
    __syncthreads();
    {
        short8v bfr[4];
        #pragma unroll
        for (int ni = 0; ni < 4; ++ni){
            int t = w*64 + ni*16 + c16;
            bfr[ni] = *(const short8v*)((const char*)Bt + fold_addr(g, t));
        }
        #pragma unroll
        for (int mi = 0; mi < 2; ++mi)
            #pragma unroll
            for (int ni = 0; ni < 4; ++ni)
                acc[mi][ni] = __builtin_amdgcn_mfma_f32_16x16x32_bf16(
                    a[mi], bfr[ni], acc[mi][ni], 0, 0, 0);
    }
    const u16* yb = ypre + boff;
    float* ob = out + boff;
    #pragma unroll
    for (int mi = 0; mi < 2; ++mi)
        #pragma unroll
        for (int r = 0; r < 4; ++r){
            int o = mi*16 + g*4 + r;
            float sc = ssl[o], sh = ssl[CC + o], rbv = rbl[o];
            #pragma unroll
            for (int ni = 0; ni < 4; ++ni){
                int t = nt0 + w*64 + ni*16 + c16;
                float v = acc[mi][ni][r] + rbv + sc * bf2f(yb[(size_t)o*NT + t]) + sh;
                ob[(size_t)o*NT + t] = v > 0.0f ? v : 0.0f;
            }
        }
}

// ---------------------------------------------------------------------------
extern "C" void kernel_launch(void* const* d_in, const int* in_sizes, int n_in,
                              void* d_out, int out_size, void* d_ws, size_t ws_size,
                              hipStream_t stream){
    const float* x     = (const float*)d_in[0];
    const float* adj   = (const float*)d_in[1];
    const float* fw    = (const float*)d_in[2];
    const float* fb    = (const float*)d_in[3];
    const float* gw    = (const float*)d_in[4];
    const float* gb    = (const float*)d_in[5];
    const float* mlpw  = (const float*)d_in[6];
    const float* mlpb  = (const float*)d_in[7];
    const float* rw    = (const float*)d_in[8];
    const float* rb    = (const float*)d_in[9];
    const float* gamma = (const float*)d_in[10];
    const float* beta  = (const float*)d_in[11];
    float* out = (float*)d_out;

    char* ws = (char*)d_ws;
    u16*   h_ws  = (u16*)(ws);                          // 134,217,728 B (h, then y_pre in place)
    u16*   g1_ws = (u16*)(ws + (size_t)BCNT*2);         // 134,217,728 B
    char*  p     = ws + (size_t)BCNT*4;
    u16*   adjb  = (u16*)p;            p += (size_t)NN*NN*2;   // 524,288 B
    u16*   wcb   = (u16*)p;            p += 3072*2;            // 6,144 B
    u16*   fwgb  = (u16*)p;            p += 4096*2;            // 8,192 B
    u16*   rwb   = (u16*)p;            p += 1024*2;            // 2,048 B
    float* ssb   = (float*)p;          p += 64*4;              // 256 B
    float* psum  = (float*)p;          p += (size_t)CC*8192*4; // 1 MB
    float* psq   = (float*)p;                                  // 1 MB
    u16*   g2b   = (u16*)d_out;        // g2 bf16 staged in d_out, consumed by k4

    k0_prep <<<NN, 256, 0, stream>>>(adj, mlpw, fw, gw, rw, adjb, wcb, fwgb, rwb);
    k1_mfma <<<dim3(NN, BB), 256, 0, stream>>>(x, fwgb, fb, gb, h_ws);
    k2_mfma<0><<<dim3(4096), 256, 0, stream>>>(adjb, h_ws, (void*)g1_ws);
    k2_mfma<0><<<dim3(4096), 256, 0, stream>>>(adjb, g1_ws, (void*)g2b);
    k4_mfma <<<dim3(512, BB), 256, 0, stream>>>(h_ws, g1_ws, g2b, wcb, mlpb,
                                                h_ws, psum, psq);
    k5_stats<<<CC, 256, 0, stream>>>(psum, psq, gamma, beta, ssb);
    k6_mfma <<<dim3(512, BB), 256, 0, stream>>>(x, rwb, rb, ssb, h_ws, out);
}